// Round 1
// baseline (29.520 us; speedup 1.0000x reference)
//
#include <hip/hip_runtime.h>

// CenterLoss: mean over samples of clip(||f[n] - centers[labels[n]]||^2).
// N=16384, C=1000, D=512 (D=512 assumed: 64 lanes x float4 x 2 per row).
// Memory-bound: 32 MiB features streamed once; centers (2 MiB) L2-resident.

__global__ __launch_bounds__(256) void center_loss_kernel(
    const float* __restrict__ feat,
    const float* __restrict__ cent,
    const int* __restrict__ labels,
    float* __restrict__ out,
    int N, float invN) {
  const int lane    = threadIdx.x & 63;
  const int wid_blk = threadIdx.x >> 6;       // wave index within block (0..3)
  const int wave    = blockIdx.x * 4 + wid_blk;
  const int nwaves  = gridDim.x * 4;

  __shared__ float wave_sums[4];
  float wave_acc = 0.0f;   // meaningful on lane 0 only

  for (int n = wave; n < N; n += nwaves) {
    const int l = labels[n];                  // wave-uniform broadcast load
    const float4* fp = reinterpret_cast<const float4*>(feat + (size_t)n * 512);
    const float4* cp = reinterpret_cast<const float4*>(cent + (size_t)l * 512);

    float s = 0.0f;
#pragma unroll
    for (int j = 0; j < 2; ++j) {
      const float4 a = fp[lane + j * 64];     // coalesced: 64 lanes x 16B = 1 KiB
      const float4 b = cp[lane + j * 64];
      const float dx = a.x - b.x;
      const float dy = a.y - b.y;
      const float dz = a.z - b.z;
      const float dw = a.w - b.w;
      s += dx * dx + dy * dy + dz * dz + dw * dw;
    }

    // 64-lane butterfly reduction (wave64!)
#pragma unroll
    for (int off = 32; off; off >>= 1) s += __shfl_xor(s, off, 64);

    if (lane == 0) {
      s = fminf(fmaxf(s, 1e-12f), 1e12f);     // per-sample clip, as in reference
      wave_acc += s;
    }
  }

  if (lane == 0) wave_sums[wid_blk] = wave_acc;
  __syncthreads();
  if (threadIdx.x == 0) {
    const float bs = wave_sums[0] + wave_sums[1] + wave_sums[2] + wave_sums[3];
    atomicAdd(out, bs * invN);                // one device-scope atomic per block
  }
}

extern "C" void kernel_launch(void* const* d_in, const int* in_sizes, int n_in,
                              void* d_out, int out_size, void* d_ws, size_t ws_size,
                              hipStream_t stream) {
  const float* feat   = (const float*)d_in[0];
  const float* cent   = (const float*)d_in[1];
  const int*   labels = (const int*)d_in[2];
  float*       out    = (float*)d_out;

  const int N = in_sizes[2];                  // 16384

  // Harness poisons d_out once and never re-poisons; we accumulate with
  // atomics, so zero it every call (graph-capture-safe async memset).
  hipMemsetAsync(out, 0, sizeof(float), stream);

  const int blocks = 1024;                    // 4096 waves = 16/CU, 4 samples/wave
  center_loss_kernel<<<blocks, 256, 0, stream>>>(feat, cent, labels, out,
                                                 N, 1.0f / (float)N);
}